// Round 2
// baseline (1985.792 us; speedup 1.0000x reference)
//
#include <hip/hip_runtime.h>

#define HN 192
#define TT 2048
#define NCLS 12
// ws layout (floats): [w0 rows 0..191][zero row 192][w1 rows 0..191][pad 256]
// row = 192 floats = 768 B.  w1 base pointer = zero row, spike j -> (j+1)*768, pad -> 0.
#define WS_FLOATS (385 * HN + 256)   // 74176 floats = 296704 B
#define LDS_FLOATS (193 * HN + 256)  // 37312 floats = 149248 B
#define L0_PAD 147456                // byte offset of zero row (192*768)

__global__ void snn_pack_k(const float* __restrict__ Wc, float* __restrict__ ws) {
  int idx = blockIdx.x * 256 + threadIdx.x;
  if (idx < HN * HN) {                       // layer 0: Wc[0][i][j] -> ws[j*192+i]
    int i = idx / HN, j = idx % HN;
    ws[j * HN + i] = Wc[idx];
  } else if (idx < 2 * HN * HN) {            // layer 1 -> rows 193..384
    int r = idx - HN * HN;
    int i = r / HN, j = r % HN;
    ws[(193 + j) * HN + i] = Wc[idx];
  } else {
    int r = idx - 2 * HN * HN;               // zero row + tail pad
    if (r < HN) ws[192 * HN + r] = 0.0f;
    if (r < 256) ws[385 * HN + r] = 0.0f;
  }
}

__device__ __forceinline__ float4 add4(float4 a, float4 b) {
  return make_float4(a.x + b.x, a.y + b.y, a.z + b.z, a.w + b.w);
}

// One wave per batch element. Lane ln owns neurons 4ln..4ln+3 (ln<48).
// Spikes exchanged purely via __ballot masks (SGPRs) — no barriers in the scan.
__global__ __launch_bounds__(64, 1) void snn_main_k(
    const float* __restrict__ x, const float* __restrict__ W_in,
    const float* __restrict__ b_in, const float* __restrict__ b_cells,
    const float* __restrict__ W_head, const float* __restrict__ b_head,
    const float* __restrict__ ws, float* __restrict__ out)
{
  extern __shared__ float lds[];             // [w0 rows + zero row][pad]
  __shared__ float feat[HN];

  const int ln = threadIdx.x;
  const int b  = blockIdx.x;
  const int ln16 = ln << 4;

  // ---- stage w0 + zero row into LDS (193 rows = 9264 float4) ----
  {
    const float4* src = (const float4*)ws;
    float4* dst = (float4*)lds;
    for (int i = ln; i < (193 * HN) / 4; i += 64) dst[i] = src[i];
    ((float4*)(lds + 193 * HN))[ln] = make_float4(0.f, 0.f, 0.f, 0.f); // pad
  }
  __syncthreads();

  // ---- per-lane constants ----
  float wi0[4], wi1[4], wi2[4], bik[4], b0k[4], b1k[4];
  #pragma unroll
  for (int k = 0; k < 4; ++k) {
    int i = 4 * ln + k;
    bool a = (i < HN);
    int ii = a ? i : 0;
    wi0[k] = a ? W_in[ii * 3 + 0] : 0.f;
    wi1[k] = a ? W_in[ii * 3 + 1] : 0.f;
    wi2[k] = a ? W_in[ii * 3 + 2] : 0.f;
    bik[k] = a ? b_in[ii]        : -1e30f;  // park idle lanes far below threshold
    b0k[k] = a ? b_cells[ii]     : 0.f;
    b1k[k] = a ? b_cells[HN + ii] : -1e30f;
  }

  const float* __restrict__ xb = x + (size_t)b * TT * 3;
  const char* ldsb = (const char*)lds;
  const char* w1z  = (const char*)ws + 192 * 768;  // zero row = base of L1 offsets

  float v0k[4] = {0, 0, 0, 0}, v1k[4] = {0, 0, 0, 0}, cntk[4] = {0, 0, 0, 0};
  unsigned long long M0[4] = {0, 0, 0, 0}, M1[4] = {0, 0, 0, 0};

  #pragma unroll 1
  for (int t = 0; t < TT; ++t) {
    // working copies (drained by extraction)
    unsigned long long e0 = M0[0], e1 = M0[1], e2 = M0[2], e3 = M0[3];
    unsigned long long f0 = M1[0], f1 = M1[1], f2 = M1[2], f3 = M1[3];
    const int S0 = (int)(__popcll(e0) + __popcll(e1) + __popcll(e2) + __popcll(e3));
    const int S1 = (int)(__popcll(f0) + __popcll(f1) + __popcll(f2) + __popcll(f3));

    auto extE = [&]() -> int {   // layer-0 spike -> LDS byte offset (pad -> zero row)
      if (!(e0 | e1 | e2 | e3)) return L0_PAD;
      if (e0) { int s = __builtin_ctzll(e0); e0 &= e0 - 1; return s * 3072; }
      if (e1) { int s = __builtin_ctzll(e1); e1 &= e1 - 1; return s * 3072 + 768; }
      if (e2) { int s = __builtin_ctzll(e2); e2 &= e2 - 1; return s * 3072 + 1536; }
      { int s = __builtin_ctzll(e3); e3 &= e3 - 1; return s * 3072 + 2304; }
    };
    auto extF = [&]() -> int {   // layer-1 spike -> byte offset from w1z (pad -> 0)
      if (!(f0 | f1 | f2 | f3)) return 0;
      if (f0) { int s = __builtin_ctzll(f0); f0 &= f0 - 1; return s * 3072 + 768; }
      if (f1) { int s = __builtin_ctzll(f1); f1 &= f1 - 1; return s * 3072 + 1536; }
      if (f2) { int s = __builtin_ctzll(f2); f2 &= f2 - 1; return s * 3072 + 2304; }
      { int s = __builtin_ctzll(f3); f3 &= f3 - 1; return s * 3072 + 3072; }
    };
    auto ld0 = [&]() -> float4 { int o = extE(); return *(const float4*)(ldsb + o + ln16); };
    auto ld1 = [&]() -> float4 { int o = extF(); return *(const float4*)(w1z + o + ln16); };

    // ---- phase 1: issue layer-1 (global/L2) gather up front (latency hides) ----
    float4 g0, g1, g2, g3, g4, g5, g6, g7, g8, g9, g10, g11, g12, g13, g14, g15;
    if (S1 > 0) { g0 = ld1(); g1 = ld1(); g2 = ld1(); g3 = ld1();
                  g4 = ld1(); g5 = ld1(); g6 = ld1(); g7 = ld1(); }
    if (S1 > 8) { g8 = ld1(); g9 = ld1(); g10 = ld1(); g11 = ld1();
                  g12 = ld1(); g13 = ld1(); g14 = ld1(); g15 = ld1(); }

    // ---- phase 2: issue layer-0 (LDS) gather ----
    float4 h0, h1, h2, h3, h4, h5, h6, h7, h8, h9, h10, h11,
           h12, h13, h14, h15, h16, h17, h18, h19, h20, h21, h22, h23;
    if (S0 > 0)  { h0 = ld0(); h1 = ld0(); h2 = ld0(); h3 = ld0();
                   h4 = ld0(); h5 = ld0(); h6 = ld0(); h7 = ld0(); }
    if (S0 > 8)  { h8 = ld0(); h9 = ld0(); h10 = ld0(); h11 = ld0();
                   h12 = ld0(); h13 = ld0(); h14 = ld0(); h15 = ld0(); }
    if (S0 > 16) { h16 = ld0(); h17 = ld0(); h18 = ld0(); h19 = ld0();
                   h20 = ld0(); h21 = ld0(); h22 = ld0(); h23 = ld0(); }

    // input projection (scalar x loads, off the critical path)
    const float x0 = xb[t * 3 + 0], x1 = xb[t * 3 + 1], x2 = xb[t * 3 + 2];

    // ---- phase 3: consume layer-0 ----
    float4 acc0 = make_float4(0.f, 0.f, 0.f, 0.f);
    if (S0 > 0)
      acc0 = add4(add4(add4(h0, h1), add4(h2, h3)), add4(add4(h4, h5), add4(h6, h7)));
    if (S0 > 8)
      acc0 = add4(acc0, add4(add4(add4(h8, h9), add4(h10, h11)),
                             add4(add4(h12, h13), add4(h14, h15))));
    if (S0 > 16)
      acc0 = add4(acc0, add4(add4(add4(h16, h17), add4(h18, h19)),
                             add4(add4(h20, h21), add4(h22, h23))));
    while (e0 | e1 | e2 | e3) {   // overflow (S0 > 24), rare
      float4 r0 = ld0(), r1 = ld0(), r2 = ld0(), r3 = ld0();
      float4 r4 = ld0(), r5 = ld0(), r6 = ld0(), r7 = ld0();
      acc0 = add4(acc0, add4(add4(add4(r0, r1), add4(r2, r3)),
                             add4(add4(r4, r5), add4(r6, r7))));
    }

    // ---- phase 4: consume layer-1 ----
    float4 acc1 = make_float4(0.f, 0.f, 0.f, 0.f);
    if (S1 > 0)
      acc1 = add4(add4(add4(g0, g1), add4(g2, g3)), add4(add4(g4, g5), add4(g6, g7)));
    if (S1 > 8)
      acc1 = add4(acc1, add4(add4(add4(g8, g9), add4(g10, g11)),
                             add4(add4(g12, g13), add4(g14, g15))));
    while (f0 | f1 | f2 | f3) {   // overflow (S1 > 16), rare
      float4 r0 = ld1(), r1 = ld1(), r2 = ld1(), r3 = ld1();
      float4 r4 = ld1(), r5 = ld1(), r6 = ld1(), r7 = ld1();
      acc1 = add4(acc1, add4(add4(add4(r0, r1), add4(r2, r3)),
                             add4(add4(r4, r5), add4(r6, r7))));
    }

    // ---- phase 5: LIF for both layers (exact fp32, reference op order) ----
    float a0k[4] = {acc0.x, acc0.y, acc0.z, acc0.w};
    float a1k[4] = {acc1.x, acc1.y, acc1.z, acc1.w};
    #pragma unroll
    for (int k = 0; k < 4; ++k) {
      float z = x0 * wi0[k] + x1 * wi1[k] + x2 * wi2[k] + bik[k];
      float a0 = z + b0k[k] + a0k[k];
      v0k[k] = v0k[k] + (a0 - v0k[k]) * 0.5f;
      bool s0 = (v0k[k] >= 1.0f);
      M0[k] = __ballot(s0);
      if (s0) v0k[k] = 0.0f;
      float a1 = b1k[k] + a1k[k] + (s0 ? 1.0f : 0.0f);
      v1k[k] = v1k[k] + (a1 - v1k[k]) * 0.5f;
      bool s1 = (v1k[k] >= 1.0f);
      M1[k] = __ballot(s1);
      if (s1) { v1k[k] = 0.0f; cntk[k] += 1.0f; }
    }
  }

  // ---- epilogue: exact mean (count * 2^-11) + head GEMV ----
  if (ln < 48) {
    const float r = 1.0f / 2048.0f;
    ((float4*)feat)[ln] = make_float4(cntk[0] * r, cntk[1] * r, cntk[2] * r, cntk[3] * r);
  }
  __syncthreads();
  if (ln < NCLS) {
    float a = b_head[ln];
    const float* wh = W_head + ln * HN;
    #pragma unroll 8
    for (int q = 0; q < HN; ++q) a += feat[q] * wh[q];
    out[b * NCLS + ln] = a;
  }
}

extern "C" void kernel_launch(void* const* d_in, const int* in_sizes, int n_in,
                              void* d_out, int out_size, void* d_ws, size_t ws_size,
                              hipStream_t stream) {
  const float* x       = (const float*)d_in[0];
  const float* W_in    = (const float*)d_in[1];
  const float* b_in    = (const float*)d_in[2];
  const float* W_cells = (const float*)d_in[3];
  const float* b_cells = (const float*)d_in[4];
  const float* W_head  = (const float*)d_in[5];
  const float* b_head  = (const float*)d_in[6];
  float* out = (float*)d_out;
  float* ws  = (float*)d_ws;   // 296704 bytes used

  snn_pack_k<<<(2 * HN * HN + 512 + 255) / 256, 256, 0, stream>>>(W_cells, ws);
  snn_main_k<<<128, 64, LDS_FLOATS * sizeof(float), stream>>>(
      x, W_in, b_in, b_cells, W_head, b_head, ws, out);
}

// Round 3
// 1457.844 us; speedup vs baseline: 1.3621x; 1.3621x over previous
//
#include <hip/hip_runtime.h>

#define HN 192
#define TT 2048
#define NCLS 12
#define ROWB 768
#define L0_PAD 147456              // byte offset of zero row in LDS
#define LDS_LIST0 149248
#define LDS_LIST1 150176
#define LDS_FEAT  151104
#define LDS_TOTAL 151872

// ws layout (floats): [w0 rows 0..191][zero row][w1 rows 0..191][256f pad]
__global__ void snn_pack_k(const float* __restrict__ Wc, float* __restrict__ ws) {
  int idx = blockIdx.x * 256 + threadIdx.x;
  if (idx < HN * HN) {                       // layer 0: Wc[0][i][j] -> ws[j*192+i]
    int i = idx / HN, j = idx % HN;
    ws[j * HN + i] = Wc[idx];
  } else if (idx < 2 * HN * HN) {            // layer 1 -> rows 193..384
    int r = idx - HN * HN;
    int i = r / HN, j = r % HN;
    ws[(193 + j) * HN + i] = Wc[idx];
  } else {
    int r = idx - 2 * HN * HN;
    if (r < HN) ws[192 * HN + r] = 0.0f;     // zero row
    if (r < 256) ws[385 * HN + r] = 0.0f;    // tail pad
  }
}

__device__ __forceinline__ float4 add4(float4 a, float4 b) {
  return make_float4(a.x + b.x, a.y + b.y, a.z + b.z, a.w + b.w);
}
__device__ __forceinline__ int lanecnt_lt(unsigned long long m) {
  return __builtin_amdgcn_mbcnt_hi((unsigned)(m >> 32),
           __builtin_amdgcn_mbcnt_lo((unsigned)m, 0u));
}

#define LD0(off) (*(const float4*)(ldsb + (unsigned)(off) + ln16))
#define LD1(off) (*(const float4*)(w1zb + (unsigned)(off) + ln16))

#define ISSUE8L(p, ca, cb) do { \
  p##0 = LD0((ca).x); p##1 = LD0((ca).y); p##2 = LD0((ca).z); p##3 = LD0((ca).w); \
  p##4 = LD0((cb).x); p##5 = LD0((cb).y); p##6 = LD0((cb).z); p##7 = LD0((cb).w); } while (0)
#define ISSUE8G(p, ca, cb) do { \
  p##0 = LD1((ca).x); p##1 = LD1((ca).y); p##2 = LD1((ca).z); p##3 = LD1((ca).w); \
  p##4 = LD1((cb).x); p##5 = LD1((cb).y); p##6 = LD1((cb).z); p##7 = LD1((cb).w); } while (0)
#define CONS8(acc, p) acc = add4(acc, \
  add4(add4(add4(p##0, p##1), add4(p##2, p##3)), add4(add4(p##4, p##5), add4(p##6, p##7))))
#define READC(da, db, base, c) do { \
  da = *(const int4*)((base) + (c) * 32); \
  db = *(const int4*)((base) + (c) * 32 + 16); } while (0)

__global__ __launch_bounds__(64, 1) void snn_main_k(
    const float* __restrict__ x, const float* __restrict__ W_in,
    const float* __restrict__ b_in, const float* __restrict__ b_cells,
    const float* __restrict__ W_head, const float* __restrict__ b_head,
    const float* __restrict__ ws, float* __restrict__ out)
{
  extern __shared__ char lds[];
  const int ln = threadIdx.x;
  const int b  = blockIdx.x;
  const int ln16 = ln << 4;
  const char* ldsb = lds;
  char* list0b = lds + LDS_LIST0;
  char* list1b = lds + LDS_LIST1;
  float* feat  = (float*)(lds + LDS_FEAT);
  const char* w1zb = (const char*)ws + 192 * ROWB;   // zero row = L1 offset base

  // stage w0 rows (9216 float4) + zero the [zero-row + guard] region
  {
    const float4* src = (const float4*)ws;
    float4* dst = (float4*)lds;
    for (int i = ln; i < (192 * ROWB) / 16; i += 64) dst[i] = src[i];
    float4 z4 = make_float4(0.f, 0.f, 0.f, 0.f);
    float4* zr = (float4*)(lds + L0_PAD);
    for (int i = ln; i < (LDS_LIST0 - L0_PAD) / 16; i += 64) zr[i] = z4;
  }
  __syncthreads();

  // per-lane constants: lane ln owns neurons 4ln..4ln+3 (ln<48 active)
  float wi0[4], wi1[4], wi2[4], zb[4], b1z[4];
  #pragma unroll
  for (int k = 0; k < 4; ++k) {
    int i = 4 * ln + k;
    bool a = (i < HN);
    int ii = a ? i : 0;
    wi0[k] = a ? W_in[ii * 3 + 0] : 0.f;
    wi1[k] = a ? W_in[ii * 3 + 1] : 0.f;
    wi2[k] = a ? W_in[ii * 3 + 2] : 0.f;
    zb[k]  = a ? (b_in[ii] + b_cells[ii]) : -1e30f;   // park idle lanes
    b1z[k] = a ? b_cells[HN + ii] : -1e30f;
  }
  const float* __restrict__ xb = x + (size_t)b * TT * 3;
  const int vo = ln * 3072;   // own row-group byte offset base

  float v0k[4] = {0, 0, 0, 0}, v1k[4] = {0, 0, 0, 0}, cntk[4] = {0, 0, 0, 0};
  int n0 = 0, n1 = 0;
  int4 c0a = {0,0,0,0}, c0b = {0,0,0,0}, c1a = {0,0,0,0}, c1b = {0,0,0,0};
  int4 d0a = {0,0,0,0}, d0b = {0,0,0,0}, d1a = {0,0,0,0}, d1b = {0,0,0,0};
  float x0 = xb[0], x1 = xb[1], x2 = xb[2];

  #pragma unroll 1
  for (int t = 0; t < TT; ++t) {
    // prefetch next step's x (consumed next iteration)
    int tn = t + 1; if (tn >= TT) tn = 0;
    const float nx0 = xb[tn * 3 + 0], nx1 = xb[tn * 3 + 1], nx2 = xb[tn * 3 + 2];

    // input projection (carried x regs, no wait)
    float zarr[4];
    #pragma unroll
    for (int k = 0; k < 4; ++k)
      zarr[k] = x0 * wi0[k] + x1 * wi1[k] + x2 * wi2[k] + zb[k];

    const int ngr0 = (n0 + 7) >> 3;
    const int ngr1 = (n1 + 7) >> 3;

    // ---- L1: issue first 16 global loads (offsets prefetched last step) ----
    float4 gA0, gA1, gA2, gA3, gA4, gA5, gA6, gA7;
    float4 gB0, gB1, gB2, gB3, gB4, gB5, gB6, gB7;
    if (ngr1 > 0) ISSUE8G(gA, d0a, d0b);
    if (ngr1 > 1) ISSUE8G(gB, d1a, d1b);

    // ---- L0: software-pipelined LDS gather, groups of 8 ----
    float4 a0v = make_float4(0.f, 0.f, 0.f, 0.f);
    float4 hA0, hA1, hA2, hA3, hA4, hA5, hA6, hA7;
    float4 hB0, hB1, hB2, hB3, hB4, hB5, hB6, hB7;
    if (ngr0 > 0) {
      int4 c2a, c2b;
      ISSUE8L(hA, c0a, c0b);            // group 0 (offsets prefetched last step)
      READC(c2a, c2b, list0b, 2);
      int g = 1;
      #pragma unroll 1
      for (; g + 1 < ngr0; g += 2) {
        ISSUE8L(hB, c1a, c1b);          // group g
        READC(c1a, c1b, list0b, g + 2);
        CONS8(a0v, hA);
        ISSUE8L(hA, c2a, c2b);          // group g+1
        READC(c2a, c2b, list0b, g + 3);
        CONS8(a0v, hB);
      }
      if (g < ngr0) {
        ISSUE8L(hB, c1a, c1b);
        CONS8(a0v, hA);
        CONS8(a0v, hB);
      } else {
        CONS8(a0v, hA);
      }
    }

    // ---- L1 consume (vmcnt domain; loads have been in flight all along) ----
    float4 a1v = make_float4(0.f, 0.f, 0.f, 0.f);
    if (ngr1 > 0) CONS8(a1v, gA);
    if (ngr1 > 1) CONS8(a1v, gB);
    if (ngr1 > 2) {                      // overflow (rare)
      #pragma unroll 1
      for (int og = 2; og < ngr1; ++og) {
        int4 ea, eb;
        READC(ea, eb, list1b, og);
        float4 r0 = LD1(ea.x), r1 = LD1(ea.y), r2 = LD1(ea.z), r3 = LD1(ea.w);
        float4 r4 = LD1(eb.x), r5 = LD1(eb.y), r6 = LD1(eb.z), r7 = LD1(eb.w);
        a1v = add4(a1v, add4(add4(add4(r0, r1), add4(r2, r3)),
                             add4(add4(r4, r5), add4(r6, r7))));
      }
    }

    // ---- LIF + ballot + compact list write ----
    const float a0arr[4] = {a0v.x, a0v.y, a0v.z, a0v.w};
    const float a1arr[4] = {a1v.x, a1v.y, a1v.z, a1v.w};
    int p0 = 0, q0 = 0;
    #pragma unroll
    for (int k = 0; k < 4; ++k) {
      float aa = zarr[k] + a0arr[k];
      v0k[k] = v0k[k] + (aa - v0k[k]) * 0.5f;      // exact reference op order
      bool s0 = (v0k[k] >= 1.0f);
      unsigned long long m0 = __ballot(s0);
      if (s0) {
        v0k[k] = 0.0f;
        *(int*)(list0b + 4 * (p0 + lanecnt_lt(m0))) = vo + k * ROWB;
      }
      p0 += (int)__popcll(m0);
      float a1 = b1z[k] + a1arr[k] + (s0 ? 1.0f : 0.0f);
      v1k[k] = v1k[k] + (a1 - v1k[k]) * 0.5f;
      bool s1 = (v1k[k] >= 1.0f);
      unsigned long long m1 = __ballot(s1);
      if (s1) {
        v1k[k] = 0.0f;
        cntk[k] += 1.0f;
        *(int*)(list1b + 4 * (q0 + lanecnt_lt(m1))) = vo + k * ROWB + ROWB;
      }
      q0 += (int)__popcll(m1);
    }
    n0 = p0; n1 = q0;
    if (ln < 8) {                         // zero-row pads -> branch-free groups
      *(int*)(list0b + 4 * (p0 + ln)) = L0_PAD;
      *(int*)(list1b + 4 * (q0 + ln)) = 0;
    }

    // ---- prefetch next step's offset chunks (L1 first: waited earlier) ----
    READC(d0a, d0b, list1b, 0);
    READC(d1a, d1b, list1b, 1);
    READC(c0a, c0b, list0b, 0);
    READC(c1a, c1b, list0b, 1);

    x0 = nx0; x1 = nx1; x2 = nx2;
  }

  // ---- epilogue: exact mean (count * 2^-11) + head GEMV ----
  if (ln < 48) {
    const float r = 1.0f / 2048.0f;
    ((float4*)feat)[ln] = make_float4(cntk[0] * r, cntk[1] * r, cntk[2] * r, cntk[3] * r);
  }
  __syncthreads();
  if (ln < NCLS) {
    float a = b_head[ln];
    const float* wh = W_head + ln * HN;
    #pragma unroll 8
    for (int q = 0; q < HN; ++q) a += feat[q] * wh[q];
    out[b * NCLS + ln] = a;
  }
}

extern "C" void kernel_launch(void* const* d_in, const int* in_sizes, int n_in,
                              void* d_out, int out_size, void* d_ws, size_t ws_size,
                              hipStream_t stream) {
  const float* x       = (const float*)d_in[0];
  const float* W_in    = (const float*)d_in[1];
  const float* b_in    = (const float*)d_in[2];
  const float* W_cells = (const float*)d_in[3];
  const float* b_cells = (const float*)d_in[4];
  const float* W_head  = (const float*)d_in[5];
  const float* b_head  = (const float*)d_in[6];
  float* out = (float*)d_out;
  float* ws  = (float*)d_ws;   // 296704 bytes used

  snn_pack_k<<<(2 * HN * HN + 512 + 255) / 256, 256, 0, stream>>>(W_cells, ws);
  snn_main_k<<<128, 64, LDS_TOTAL, stream>>>(
      x, W_in, b_in, b_cells, W_head, b_head, ws, out);
}

// Round 4
// 1072.894 us; speedup vs baseline: 1.8509x; 1.3588x over previous
//
#include <hip/hip_runtime.h>

#define HN 192
#define TT 2048
#define NCLS 12
#define ROWB 768
// LDS layout (bytes)
#define L0_PAD    147456           // zero row (768B) + guard to LDS_LIST0
#define LDS_LIST0 149248           // wave0-private spike list (<=200 * 4B)
#define LDS_LIST1 150080           // wave1-private spike list
#define LDS_S0BUF 150912           // two 1024B s0 buffers (double-buffered by t&1)
#define LDS_FEAT  152960           // 768B
#define LDS_TOTAL 153728

// ws layout (floats): [w0 rows 0..191][zero row][w1 rows 0..191][256f pad]
__global__ void snn_pack_k(const float* __restrict__ Wc, float* __restrict__ ws) {
  int idx = blockIdx.x * 256 + threadIdx.x;
  if (idx < HN * HN) {                       // layer 0: Wc[0][i][j] -> ws[j*192+i]
    int i = idx / HN, j = idx % HN;
    ws[j * HN + i] = Wc[idx];
  } else if (idx < 2 * HN * HN) {            // layer 1 -> rows 193..384
    int r = idx - HN * HN;
    int i = r / HN, j = r % HN;
    ws[(193 + j) * HN + i] = Wc[idx];
  } else {
    int r = idx - 2 * HN * HN;
    if (r < HN) ws[192 * HN + r] = 0.0f;     // zero row
    if (r < 256) ws[385 * HN + r] = 0.0f;    // tail pad
  }
}

__device__ __forceinline__ float4 add4(float4 a, float4 b) {
  return make_float4(a.x + b.x, a.y + b.y, a.z + b.z, a.w + b.w);
}
__device__ __forceinline__ int lanecnt_lt(unsigned long long m) {
  return __builtin_amdgcn_mbcnt_hi((unsigned)(m >> 32),
           __builtin_amdgcn_mbcnt_lo((unsigned)m, 0u));
}

#define LD0(off) (*(const float4*)(ldsb + (unsigned)(off) + ln16))
#define LD1(off) (*(const float4*)(w1zb + (unsigned)(off) + ln16))

#define ISSUE8L(p, ca, cb) do { \
  p##0 = LD0((ca).x); p##1 = LD0((ca).y); p##2 = LD0((ca).z); p##3 = LD0((ca).w); \
  p##4 = LD0((cb).x); p##5 = LD0((cb).y); p##6 = LD0((cb).z); p##7 = LD0((cb).w); } while (0)
#define ISSUE8G(p, ca, cb) do { \
  p##0 = LD1((ca).x); p##1 = LD1((ca).y); p##2 = LD1((ca).z); p##3 = LD1((ca).w); \
  p##4 = LD1((cb).x); p##5 = LD1((cb).y); p##6 = LD1((cb).z); p##7 = LD1((cb).w); } while (0)
#define CONS8(acc, p) acc = add4(acc, \
  add4(add4(add4(p##0, p##1), add4(p##2, p##3)), add4(add4(p##4, p##5), add4(p##6, p##7))))
#define READC(da, db, base, c) do { \
  da = *(const int4*)((base) + (c) * 32); \
  db = *(const int4*)((base) + (c) * 32 + 16); } while (0)

// 128 threads = 2 waves per batch element. Wave 0: layer-0 pipeline (LDS
// weights). Wave 1: layer-1 pipeline (global/L2 weights, loads in flight
// across the barrier). One __syncthreads per timestep; the only cross-wave
// handoff is the double-buffered s0(t) vector.
__global__ __launch_bounds__(128, 1) void snn_main_k(
    const float* __restrict__ x, const float* __restrict__ W_in,
    const float* __restrict__ b_in, const float* __restrict__ b_cells,
    const float* __restrict__ W_head, const float* __restrict__ b_head,
    const float* __restrict__ ws, float* __restrict__ out)
{
  extern __shared__ char lds[];
  const int tid = threadIdx.x;
  const int ln  = tid & 63;
  const bool isW0 = (tid < 64);
  const int b  = blockIdx.x;
  const int ln16 = ln << 4;
  const char* ldsb = lds;
  char* list0b = lds + LDS_LIST0;
  char* list1b = lds + LDS_LIST1;
  char* s0b    = lds + LDS_S0BUF;
  float* feat  = (float*)(lds + LDS_FEAT);
  const char* w1zb = (const char*)ws + 192 * ROWB;   // zero row = L1 offset base

  // stage w0 rows (9216 float4, both waves) + zero [zero-row .. s0 buffers]
  {
    const float4* src = (const float4*)ws;
    float4* dst = (float4*)lds;
    for (int i = tid; i < (192 * ROWB) / 16; i += 128) dst[i] = src[i];
    float4 z4 = make_float4(0.f, 0.f, 0.f, 0.f);
    float4* zr = (float4*)(lds + L0_PAD);
    for (int i = tid; i < (LDS_FEAT - L0_PAD) / 16; i += 128) zr[i] = z4;
  }
  __syncthreads();

  // per-lane constants: lane ln owns neurons 4ln..4ln+3 (ln<48 active)
  float wi0[4], wi1[4], wi2[4], zb[4], b1z[4];
  #pragma unroll
  for (int k = 0; k < 4; ++k) {
    int i = 4 * ln + k;
    bool a = (i < HN);
    int ii = a ? i : 0;
    wi0[k] = a ? W_in[ii * 3 + 0] : 0.f;
    wi1[k] = a ? W_in[ii * 3 + 1] : 0.f;
    wi2[k] = a ? W_in[ii * 3 + 2] : 0.f;
    zb[k]  = a ? (b_in[ii] + b_cells[ii]) : -1e30f;   // park idle lanes
    b1z[k] = a ? b_cells[HN + ii] : -1e30f;
  }
  const float* __restrict__ xb = x + (size_t)b * TT * 3;
  const int vo = ln * 3072;   // own row-group byte offset base

  // wave-0 state
  float v0k[4] = {0, 0, 0, 0};
  int n0 = 0;
  int4 c0a = {0,0,0,0}, c0b = {0,0,0,0}, c1a = {0,0,0,0}, c1b = {0,0,0,0};
  float x0 = xb[0], x1 = xb[1], x2 = xb[2];
  // wave-1 state
  float v1k[4] = {0, 0, 0, 0}, cntk[4] = {0, 0, 0, 0};
  int ngl = 0;
  int4 d0a = {0,0,0,0}, d0b = {0,0,0,0}, d1a = {0,0,0,0}, d1b = {0,0,0,0};
  float4 gA0, gA1, gA2, gA3, gA4, gA5, gA6, gA7;       // in-flight L1 gather
  float4 gB0, gB1, gB2, gB3, gB4, gB5, gB6, gB7;

  #pragma unroll 1
  for (int t = 0; t < TT; ++t) {
    float4 a1sum = make_float4(0.f, 0.f, 0.f, 0.f);
    if (isW0) {
      // ---------------- wave 0: layer-0 pipeline ----------------
      int tn = t + 1; if (tn >= TT) tn = 0;
      const float nx0 = xb[tn * 3 + 0], nx1 = xb[tn * 3 + 1], nx2 = xb[tn * 3 + 2];
      float zarr[4];
      #pragma unroll
      for (int k = 0; k < 4; ++k)
        zarr[k] = x0 * wi0[k] + x1 * wi1[k] + x2 * wi2[k] + zb[k];

      const int ngr0 = (n0 + 7) >> 3;
      float4 a0v = make_float4(0.f, 0.f, 0.f, 0.f);
      float4 hA0, hA1, hA2, hA3, hA4, hA5, hA6, hA7;
      float4 hB0, hB1, hB2, hB3, hB4, hB5, hB6, hB7;
      if (ngr0 > 0) {
        int4 c2a, c2b;
        ISSUE8L(hA, c0a, c0b);            // group 0 (offsets prefetched last step)
        READC(c2a, c2b, list0b, 2);
        int g = 1;
        #pragma unroll 1
        for (; g + 1 < ngr0; g += 2) {
          ISSUE8L(hB, c1a, c1b);
          READC(c1a, c1b, list0b, g + 2);
          CONS8(a0v, hA);
          ISSUE8L(hA, c2a, c2b);
          READC(c2a, c2b, list0b, g + 3);
          CONS8(a0v, hB);
        }
        if (g < ngr0) {
          ISSUE8L(hB, c1a, c1b);
          CONS8(a0v, hA);
          CONS8(a0v, hB);
        } else {
          CONS8(a0v, hA);
        }
      }

      // LIF layer 0 (exact reference op order)
      const float a0arr[4] = {a0v.x, a0v.y, a0v.z, a0v.w};
      float s0f[4];
      unsigned long long mm[4];
      #pragma unroll
      for (int k = 0; k < 4; ++k) {
        float aa = zarr[k] + a0arr[k];
        v0k[k] = v0k[k] + (aa - v0k[k]) * 0.5f;
        bool s0 = (v0k[k] >= 1.0f);
        mm[k] = __ballot(s0);
        s0f[k] = s0 ? 1.0f : 0.0f;
        if (s0) v0k[k] = 0.0f;
      }
      // publish s0(t) (double-buffered by t&1)
      if (ln < 48)
        *(float4*)(s0b + ((t & 1) << 10) + ln16) =
            make_float4(s0f[0], s0f[1], s0f[2], s0f[3]);
      // compact own spike list for next step
      int p0 = 0;
      #pragma unroll
      for (int k = 0; k < 4; ++k) {
        if (s0f[k] != 0.f)
          *(int*)(list0b + 4 * (p0 + lanecnt_lt(mm[k]))) = vo + k * ROWB;
        p0 += (int)__popcll(mm[k]);
      }
      if (ln < 8) *(int*)(list0b + 4 * (p0 + ln)) = L0_PAD;
      n0 = p0;
      READC(c0a, c0b, list0b, 0);
      READC(c1a, c1b, list0b, 1);
      x0 = nx0; x1 = nx1; x2 = nx2;
    } else {
      // ---------------- wave 1: consume in-flight L1 gather ----------------
      if (ngl > 0) CONS8(a1sum, gA);
      if (ngl > 1) CONS8(a1sum, gB);
      if (ngl > 2) {                       // overflow (rare); list1 still intact
        #pragma unroll 1
        for (int og = 2; og < ngl; ++og) {
          int4 ea, eb;
          READC(ea, eb, list1b, og);
          float4 r0 = LD1(ea.x), r1 = LD1(ea.y), r2 = LD1(ea.z), r3 = LD1(ea.w);
          float4 r4 = LD1(eb.x), r5 = LD1(eb.y), r6 = LD1(eb.z), r7 = LD1(eb.w);
          a1sum = add4(a1sum, add4(add4(add4(r0, r1), add4(r2, r3)),
                                   add4(add4(r4, r5), add4(r6, r7))));
        }
      }
    }

    __syncthreads();   // s0(t) published; one barrier per step

    if (!isW0) {
      // ---------------- wave 1: LIF layer 1 + issue next gather ----------------
      float4 s0v = *(const float4*)(s0b + ((t & 1) << 10) + ln16);
      const float a1arr[4] = {a1sum.x + s0v.x, a1sum.y + s0v.y,
                              a1sum.z + s0v.z, a1sum.w + s0v.w};
      int q0 = 0;
      #pragma unroll
      for (int k = 0; k < 4; ++k) {
        float a1 = b1z[k] + a1arr[k];
        v1k[k] = v1k[k] + (a1 - v1k[k]) * 0.5f;
        bool s1 = (v1k[k] >= 1.0f);
        unsigned long long m1 = __ballot(s1);
        if (s1) {
          v1k[k] = 0.0f;
          cntk[k] += 1.0f;
          *(int*)(list1b + 4 * (q0 + lanecnt_lt(m1))) = vo + k * ROWB + ROWB;
        }
        q0 += (int)__popcll(m1);
      }
      if (ln < 8) *(int*)(list1b + 4 * (q0 + ln)) = 0;
      const int ngr1 = (q0 + 7) >> 3;
      READC(d0a, d0b, list1b, 0);
      READC(d1a, d1b, list1b, 1);
      if (ngr1 > 0) ISSUE8G(gA, d0a, d0b);   // fly across the next barrier
      if (ngr1 > 1) ISSUE8G(gB, d1a, d1b);
      ngl = ngr1;
    }
  }

  // ---- epilogue: exact mean (count * 2^-11) + head GEMV ----
  if (!isW0 && ln < 48) {
    const float r = 1.0f / 2048.0f;
    ((float4*)feat)[ln] = make_float4(cntk[0] * r, cntk[1] * r, cntk[2] * r, cntk[3] * r);
  }
  __syncthreads();
  if (tid < NCLS) {
    float a = b_head[tid];
    const float* wh = W_head + tid * HN;
    #pragma unroll 8
    for (int q = 0; q < HN; ++q) a += feat[q] * wh[q];
    out[b * NCLS + tid] = a;
  }
}

extern "C" void kernel_launch(void* const* d_in, const int* in_sizes, int n_in,
                              void* d_out, int out_size, void* d_ws, size_t ws_size,
                              hipStream_t stream) {
  const float* x       = (const float*)d_in[0];
  const float* W_in    = (const float*)d_in[1];
  const float* b_in    = (const float*)d_in[2];
  const float* W_cells = (const float*)d_in[3];
  const float* b_cells = (const float*)d_in[4];
  const float* W_head  = (const float*)d_in[5];
  const float* b_head  = (const float*)d_in[6];
  float* out = (float*)d_out;
  float* ws  = (float*)d_ws;   // 296704 bytes used

  snn_pack_k<<<(2 * HN * HN + 512 + 255) / 256, 256, 0, stream>>>(W_cells, ws);
  snn_main_k<<<128, 128, LDS_TOTAL, stream>>>(
      x, W_in, b_in, b_cells, W_head, b_head, ws, out);
}